// Round 2
// baseline (164.784 us; speedup 1.0000x reference)
//
#include <hip/hip_runtime.h>

typedef __attribute__((ext_vector_type(8))) short short8;
typedef __attribute__((ext_vector_type(4))) float f32x4;
typedef __attribute__((ext_vector_type(4))) unsigned short us4;

typedef unsigned int __attribute__((address_space(3))) lds_u32;
typedef const unsigned int __attribute__((address_space(1))) glb_u32;

__device__ __forceinline__ unsigned short f2bf(float f){
  unsigned int u = __float_as_uint(f);
  u = (u + 0x7FFFu + ((u >> 16) & 1u)) >> 16;
  return (unsigned short)u;
}
__device__ __forceinline__ float bf2f(unsigned short h){
  return __uint_as_float(((unsigned int)h) << 16);
}

// ---------------- fused prep: weight cast | rmsnorm(x) | lo-scan --------------
__global__ __launch_bounds__(256)
void prep(const float* __restrict__ wq, const float* __restrict__ wo,
          unsigned short* __restrict__ wqb, unsigned short* __restrict__ wob,
          const float* __restrict__ x, unsigned short* __restrict__ h,
          const unsigned char* __restrict__ mb, int* __restrict__ lo){
  int blk = blockIdx.x;
  int t = threadIdx.x;
  if (blk < 2560) {                                  // weight f32->bf16
    int i = blk * 256 + t;
    const int n1 = 1536 * 1024 / 4;
    float4 v = (i < n1) ? ((const float4*)wq)[i] : ((const float4*)wo)[i - n1];
    us4 o = { f2bf(v.x), f2bf(v.y), f2bf(v.z), f2bf(v.w) };
    if (i < n1) ((us4*)wqb)[i] = o;
    else        ((us4*)wob)[i - n1] = o;
    return;
  }
  if (blk < 2560 + 4096) {                           // rmsnorm over D=1024
    int row = blk - 2560;
    float4 v = ((const float4*)(x + (size_t)row * 1024))[t];
    float ss = v.x*v.x + v.y*v.y + v.z*v.z + v.w*v.w;
    #pragma unroll
    for (int m = 1; m < 64; m <<= 1) ss += __shfl_xor(ss, m);
    __shared__ float wsum[4];
    if ((t & 63) == 0) wsum[t >> 6] = ss;
    __syncthreads();
    float tot = wsum[0] + wsum[1] + wsum[2] + wsum[3];
    float sc = rsqrtf(tot * (1.f/1024.f) + 1.1920929e-07f);
    us4 o = { f2bf(v.x*sc), f2bf(v.y*sc), f2bf(v.z*sc), f2bf(v.w*sc) };
    *(us4*)(h + (size_t)row * 1024 + t * 4) = o;
    return;
  }
  // lo[q] = max(q-1023, last reset <= q); auto-detect mask dtype
  int b = blk - 2560 - 4096;
  __shared__ int flag_s;
  if (t == 0) flag_s = 0;
  __syncthreads();
  if (t < 64 && (t & 3) != 0 && mb[t] != 0) atomicOr(&flag_s, 1);
  __syncthreads();
  const bool isb = (flag_s != 0);
  const int* mi = (const int*)mb;
  int tmax = 0;
  int mvals[8];
  #pragma unroll
  for (int j = 0; j < 8; j++) {
    int p = t * 8 + j;
    int mv = isb ? (int)mb[b*2048 + p] : mi[b*2048 + p];
    mvals[j] = mv;
    if (mv) tmax = p;
  }
  __shared__ int sm[256];
  sm[t] = tmax;
  __syncthreads();
  for (int offd = 1; offd < 256; offd <<= 1) {
    int v = (t >= offd) ? sm[t - offd] : 0;
    __syncthreads();
    if (t >= offd) sm[t] = max(sm[t], v);
    __syncthreads();
  }
  int run = (t > 0) ? sm[t - 1] : 0;
  #pragma unroll
  for (int j = 0; j < 8; j++) {
    int p = t * 8 + j;
    if (mvals[j]) run = p;
    int l = run, wlo = p - 1023;
    if (wlo > l) l = wlo;
    if (l < 0) l = 0;
    lo[b*2048 + p] = l;
  }
}

// ---------------- NT GEMM (m97 structure): C[M,N] = A[M,K] * B[N,K]^T --------
// 128x128 tile, BK=64, 4 waves (2x2), linear LDS, global_load_lds width-16.
template<bool BF_OUT, bool RES>
__global__ __launch_bounds__(256)
void gemm_nt(const unsigned short* __restrict__ A, const unsigned short* __restrict__ B,
             int M, int N, int K, float* __restrict__ Cf, unsigned short* __restrict__ Cb,
             const float* __restrict__ resid){
  __shared__ __align__(16) short As[128 * 64];
  __shared__ __align__(16) short Bs[128 * 64];
  const int nbn = N >> 7;
  const int bm = blockIdx.x / nbn;
  const int bn = blockIdx.x % nbn;
  const int t = threadIdx.x;
  const int lane = t & 63;
  const int wv = t >> 6;
  const int wm = (wv >> 1) * 64, wn = (wv & 1) * 64;
  const int lr = lane & 15, lg = lane >> 4;
  const int l8 = lane >> 3;          // row within 1KB chunk
  const int c8 = (lane & 7) * 8;     // col (shorts) within row

  f32x4 acc[4][4];
  #pragma unroll
  for (int m = 0; m < 4; m++)
    #pragma unroll
    for (int n = 0; n < 4; n++) acc[m][n] = (f32x4){0.f,0.f,0.f,0.f};

  const unsigned short* Ab = A + (size_t)(bm * 128) * K;
  const unsigned short* Bb = B + (size_t)(bn * 128) * K;

  for (int kt = 0; kt < K; kt += 64) {
    #pragma unroll
    for (int i = 0; i < 4; i++) {
      int chunk = wv * 4 + i;            // 16 chunks of 1KB each, per operand
      int row = chunk * 8 + l8;
      __builtin_amdgcn_global_load_lds((glb_u32*)(Ab + (size_t)row * K + kt + c8),
                                       (lds_u32*)&As[chunk * 512], 16, 0, 0);
      __builtin_amdgcn_global_load_lds((glb_u32*)(Bb + (size_t)row * K + kt + c8),
                                       (lds_u32*)&Bs[chunk * 512], 16, 0, 0);
    }
    __syncthreads();
    #pragma unroll
    for (int kk = 0; kk < 2; kk++) {
      short8 af[4], bfr[4];
      #pragma unroll
      for (int m = 0; m < 4; m++) af[m] = *(const short8*)&As[(wm + m*16 + lr)*64 + kk*32 + lg*8];
      #pragma unroll
      for (int n = 0; n < 4; n++) bfr[n] = *(const short8*)&Bs[(wn + n*16 + lr)*64 + kk*32 + lg*8];
      #pragma unroll
      for (int m = 0; m < 4; m++)
        #pragma unroll
        for (int n = 0; n < 4; n++)
          acc[m][n] = __builtin_amdgcn_mfma_f32_16x16x32_bf16(af[m], bfr[n], acc[m][n], 0, 0, 0);
    }
    __syncthreads();
  }
  #pragma unroll
  for (int m = 0; m < 4; m++)
    #pragma unroll
    for (int n = 0; n < 4; n++)
      #pragma unroll
      for (int r = 0; r < 4; r++) {
        int grow = bm*128 + wm + m*16 + lg*4 + r;
        int gcol = bn*128 + wn + n*16 + lr;
        size_t idx = (size_t)grow * N + gcol;
        if (BF_OUT) { Cb[idx] = f2bf(acc[m][n][r]); }
        else {
          float v = acc[m][n][r];
          if (RES) v += resid[idx];
          Cf[idx] = v;
        }
      }
}

// ---------------- per-head RMSNorm + RoPE, split/layout q,k,v ----------------
__global__ __launch_bounds__(256)
void post_qkv(const unsigned short* __restrict__ qkv,
              unsigned short* __restrict__ Qb, unsigned short* __restrict__ Kb,
              unsigned short* __restrict__ Vt){
  int w = blockIdx.x * 4 + (threadIdx.x >> 6);
  int lane = threadIdx.x & 63;
  int head = w % 24;
  int row  = w / 24;                       // [0, 4096)
  int b = row >> 11, pos = row & 2047;
  int off = head < 16 ? head * 64 : (head < 20 ? 1024 + (head-16)*64 : 1280 + (head-20)*64);
  float val = bf2f(qkv[(size_t)row * 1536 + off + lane]);
  if (head < 20) {
    float ss = val * val;
    #pragma unroll
    for (int m = 1; m < 64; m <<= 1) ss += __shfl_xor(ss, m);
    val *= rsqrtf(ss * (1.f/64.f) + 1.1920929e-07f);
    float part = __shfl_xor(val, 32);
    int i = lane & 31;
    float f = (float)pos * exp2f((float)i * (-13.287712379549449f / 32.f));
    float s, c; sincosf(f, &s, &c);
    val = (lane < 32) ? (val * c - part * s) : (part * s + val * c);
  }
  unsigned short o = f2bf(val);
  if (head < 16)      Qb[((size_t)((b*16 + head     )*2048 + pos))*64 + lane] = o;
  else if (head < 20) Kb[((size_t)((b*4  + head - 16)*2048 + pos))*64 + lane] = o;
  else                Vt[((size_t)((b*4  + head - 20)*64 + lane))*2048 + pos] = o; // transposed
}

// ---------------- attention: one wave = 16 queries, contiguous key range ------
__global__ __launch_bounds__(256)
void attn(const unsigned short* __restrict__ Qb, const unsigned short* __restrict__ Kb,
          const unsigned short* __restrict__ Vt, const int* __restrict__ lo,
          unsigned short* __restrict__ Y){
  int blk = blockIdx.x;
  int qt = blk & 31, h = (blk >> 5) & 15, b = blk >> 9;
  int wv = threadIdx.x >> 6, lane = threadIdx.x & 63;
  int lr = lane & 15, lg = lane >> 4;
  int q0 = qt * 64 + wv * 16;
  const unsigned short* Qh = Qb + ((size_t)(b*16 + h)) * 2048 * 64;
  int kvh = h >> 2;
  const unsigned short* Kh = Kb + ((size_t)(b*4 + kvh)) * 2048 * 64;
  const unsigned short* Vh = Vt + ((size_t)(b*4 + kvh)) * 64 * 2048;
  short8 qa0 = *(const short8*)(Qh + (size_t)(q0 + lr) * 64 + lg * 8);
  short8 qa1 = *(const short8*)(Qh + (size_t)(q0 + lr) * 64 + 32 + lg * 8);
  const int* lop = lo + b * 2048 + q0;
  int4 mlv = *(const int4*)(lop + lg * 4);
  int mylo[4] = {mlv.x, mlv.y, mlv.z, mlv.w};
  int kc0 = lop[0] & ~31;
  int kend = q0 + 15;
  f32x4 oacc[4];
  #pragma unroll
  for (int n = 0; n < 4; n++) oacc[n] = (f32x4){0.f,0.f,0.f,0.f};
  float den[4] = {0.f,0.f,0.f,0.f};
  __shared__ __align__(16) short Pl[4][16 * 40];
  short* Pw = Pl[wv];
  for (int kc = kc0; kc <= kend; kc += 32) {
    f32x4 s[2];
    #pragma unroll
    for (int n = 0; n < 2; n++) {
      int kr = kc + n*16 + lr;
      int krl = min(kr, 2047);
      short8 k0 = *(const short8*)(Kh + (size_t)krl * 64 + lg * 8);
      short8 k1 = *(const short8*)(Kh + (size_t)krl * 64 + 32 + lg * 8);
      f32x4 z = (f32x4){0.f,0.f,0.f,0.f};
      z = __builtin_amdgcn_mfma_f32_16x16x32_bf16(qa0, k0, z, 0, 0, 0);
      z = __builtin_amdgcn_mfma_f32_16x16x32_bf16(qa1, k1, z, 0, 0, 0);
      s[n] = z;
    }
    #pragma unroll
    for (int n = 0; n < 2; n++)
      #pragma unroll
      for (int r = 0; r < 4; r++) {
        int krow = kc + n*16 + lr;
        int qrow = q0 + lg*4 + r;
        bool valid = (krow >= mylo[r]) && (krow <= qrow);
        float p = valid ? __expf(s[n][r] * 0.125f) : 0.f;
        den[r] += p;
        Pw[(lg*4 + r) * 40 + n*16 + lr] = (short)f2bf(p);
      }
    short8 pa = *(const short8*)&Pw[lr * 40 + lg * 8];
    int vc = min(kc + lg * 8, 2040);
    #pragma unroll
    for (int n = 0; n < 4; n++) {
      short8 vb = *(const short8*)(Vh + (size_t)(n*16 + lr) * 2048 + vc);
      oacc[n] = __builtin_amdgcn_mfma_f32_16x16x32_bf16(pa, vb, oacc[n], 0, 0, 0);
    }
  }
  #pragma unroll
  for (int r = 0; r < 4; r++)
    #pragma unroll
    for (int m = 1; m < 16; m <<= 1) den[r] += __shfl_xor(den[r], m);
  #pragma unroll
  for (int n = 0; n < 4; n++)
    #pragma unroll
    for (int r = 0; r < 4; r++) {
      int qrow = q0 + lg*4 + r;
      Y[((size_t)(b*2048 + qrow)) * 1024 + h*64 + n*16 + lr] = f2bf(oacc[n][r] / den[r]);
    }
}

extern "C" void kernel_launch(void* const* d_in, const int* in_sizes, int n_in,
                              void* d_out, int out_size, void* d_ws, size_t ws_size,
                              hipStream_t stream){
  const float* x    = (const float*)d_in[0];
  const float* wqkv = (const float*)d_in[1];
  const float* wout = (const float*)d_in[2];
  const unsigned char* mask = (const unsigned char*)d_in[3];
  float* out = (float*)d_out;
  char* ws = (char*)d_ws;
  size_t off = 0;
  auto alloc = [&](size_t bytes) -> void* {
    void* p = ws + off;
    off += (bytes + 255) & ~(size_t)255;
    return p;
  };
  unsigned short* wq_b  = (unsigned short*)alloc((size_t)1536*1024*2);
  unsigned short* wo_b  = (unsigned short*)alloc((size_t)1024*1024*2);
  unsigned short* h_b   = (unsigned short*)alloc((size_t)4096*1024*2);
  unsigned short* qkv_b = (unsigned short*)alloc((size_t)4096*1536*2);
  unsigned short* q_b   = (unsigned short*)alloc((size_t)4096*1024*2);
  unsigned short* k_b   = (unsigned short*)alloc((size_t)4096*256*2);
  unsigned short* vt_b  = (unsigned short*)alloc((size_t)4096*256*2);
  unsigned short* y_b   = (unsigned short*)alloc((size_t)4096*1024*2);
  int* lo               = (int*)alloc((size_t)4096*4);

  prep<<<2560 + 4096 + 2, 256, 0, stream>>>(wqkv, wout, wq_b, wo_b, x, h_b, mask, lo);
  gemm_nt<true,  false><<<32*12, 256, 0, stream>>>(h_b, wq_b, 4096, 1536, 1024, nullptr, qkv_b, nullptr);
  post_qkv<<<24576, 256, 0, stream>>>(qkv_b, q_b, k_b, vt_b);
  attn<<<1024, 256, 0, stream>>>(q_b, k_b, vt_b, lo, y_b);
  gemm_nt<false, true><<<32*8, 256, 0, stream>>>(y_b, wo_b, 4096, 1024, 1024, out, nullptr, x);
}

// Round 3
// 156.634 us; speedup vs baseline: 1.0520x; 1.0520x over previous
//
#include <hip/hip_runtime.h>

typedef __attribute__((ext_vector_type(8))) short short8;
typedef __attribute__((ext_vector_type(4))) float f32x4;
typedef __attribute__((ext_vector_type(4))) unsigned short us4;

typedef unsigned int __attribute__((address_space(3))) lds_u32;
typedef const unsigned int __attribute__((address_space(1))) glb_u32;

__device__ __forceinline__ unsigned short f2bf(float f){
  unsigned int u = __float_as_uint(f);
  u = (u + 0x7FFFu + ((u >> 16) & 1u)) >> 16;
  return (unsigned short)u;
}
__device__ __forceinline__ float bf2f(unsigned short h){
  return __uint_as_float(((unsigned int)h) << 16);
}

// ---------------- fused prep: weight cast | rmsnorm(x) | lo-scan --------------
__global__ __launch_bounds__(256)
void prep(const float* __restrict__ wq, const float* __restrict__ wo,
          unsigned short* __restrict__ wqb, unsigned short* __restrict__ wob,
          const float* __restrict__ x, unsigned short* __restrict__ h,
          const unsigned char* __restrict__ mb, int* __restrict__ lo){
  int blk = blockIdx.x;
  int t = threadIdx.x;
  if (blk < 2560) {                                  // weight f32->bf16
    int i = blk * 256 + t;
    const int n1 = 1536 * 1024 / 4;
    float4 v = (i < n1) ? ((const float4*)wq)[i] : ((const float4*)wo)[i - n1];
    us4 o = { f2bf(v.x), f2bf(v.y), f2bf(v.z), f2bf(v.w) };
    if (i < n1) ((us4*)wqb)[i] = o;
    else        ((us4*)wob)[i - n1] = o;
    return;
  }
  if (blk < 2560 + 4096) {                           // rmsnorm over D=1024
    int row = blk - 2560;
    float4 v = ((const float4*)(x + (size_t)row * 1024))[t];
    float ss = v.x*v.x + v.y*v.y + v.z*v.z + v.w*v.w;
    #pragma unroll
    for (int m = 1; m < 64; m <<= 1) ss += __shfl_xor(ss, m);
    __shared__ float wsum[4];
    if ((t & 63) == 0) wsum[t >> 6] = ss;
    __syncthreads();
    float tot = wsum[0] + wsum[1] + wsum[2] + wsum[3];
    float sc = rsqrtf(tot * (1.f/1024.f) + 1.1920929e-07f);
    us4 o = { f2bf(v.x*sc), f2bf(v.y*sc), f2bf(v.z*sc), f2bf(v.w*sc) };
    *(us4*)(h + (size_t)row * 1024 + t * 4) = o;
    return;
  }
  // lo[q] = max(q-1023, last reset <= q); auto-detect mask dtype
  int b = blk - 2560 - 4096;
  __shared__ int flag_s;
  if (t == 0) flag_s = 0;
  __syncthreads();
  if (t < 64 && (t & 3) != 0 && mb[t] != 0) atomicOr(&flag_s, 1);
  __syncthreads();
  const bool isb = (flag_s != 0);
  const int* mi = (const int*)mb;
  int tmax = 0;
  int mvals[8];
  #pragma unroll
  for (int j = 0; j < 8; j++) {
    int p = t * 8 + j;
    int mv = isb ? (int)mb[b*2048 + p] : mi[b*2048 + p];
    mvals[j] = mv;
    if (mv) tmax = p;
  }
  __shared__ int sm[256];
  sm[t] = tmax;
  __syncthreads();
  for (int offd = 1; offd < 256; offd <<= 1) {
    int v = (t >= offd) ? sm[t - offd] : 0;
    __syncthreads();
    if (t >= offd) sm[t] = max(sm[t], v);
    __syncthreads();
  }
  int run = (t > 0) ? sm[t - 1] : 0;
  #pragma unroll
  for (int j = 0; j < 8; j++) {
    int p = t * 8 + j;
    if (mvals[j]) run = p;
    int l = run, wlo = p - 1023;
    if (wlo > l) l = wlo;
    if (l < 0) l = 0;
    lo[b*2048 + p] = l;
  }
}

// ---------------- NT GEMM, 2-phase double-buffered (counted vmcnt) -----------
// C[M,N] = A[M,K] * B[N,K]^T. 128x128 tile, BK=64, 4 waves, K=1024 (16 steps).
template<bool BF_OUT, bool RES>
__global__ __launch_bounds__(256)
void gemm_nt(const unsigned short* __restrict__ A, const unsigned short* __restrict__ B,
             int M, int N, int K, float* __restrict__ Cf, unsigned short* __restrict__ Cb,
             const float* __restrict__ resid){
  __shared__ __align__(16) short As[2][128 * 64];
  __shared__ __align__(16) short Bs[2][128 * 64];
  const int nbn = N >> 7;
  const int nwg = gridDim.x;
  const int cpx = nwg >> 3;                      // nwg % 8 == 0 guaranteed
  const int swz = (blockIdx.x & 7) * cpx + (blockIdx.x >> 3);
  const int bm = swz / nbn;
  const int bn = swz % nbn;
  const int t = threadIdx.x;
  const int lane = t & 63;
  const int wv = t >> 6;
  const int wm = (wv >> 1) * 64, wn = (wv & 1) * 64;
  const int lr = lane & 15, lg = lane >> 4;
  const int l8 = lane >> 3;          // row within 1KB chunk
  const int c8 = (lane & 7) * 8;     // col (shorts) within row

  f32x4 acc[4][4];
  #pragma unroll
  for (int m = 0; m < 4; m++)
    #pragma unroll
    for (int n = 0; n < 4; n++) acc[m][n] = (f32x4){0.f,0.f,0.f,0.f};

  const unsigned short* Ab = A + (size_t)(bm * 128) * K;
  const unsigned short* Bb = B + (size_t)(bn * 128) * K;

  #define STAGE(buf, kt) do { \
    _Pragma("unroll") \
    for (int i = 0; i < 4; i++) { \
      int chunk = wv * 4 + i; \
      int row = chunk * 8 + l8; \
      __builtin_amdgcn_global_load_lds((glb_u32*)(Ab + (size_t)row * K + (kt) + c8), \
                                       (lds_u32*)&As[buf][chunk * 512], 16, 0, 0); \
      __builtin_amdgcn_global_load_lds((glb_u32*)(Bb + (size_t)row * K + (kt) + c8), \
                                       (lds_u32*)&Bs[buf][chunk * 512], 16, 0, 0); \
    } \
  } while (0)

  auto COMPUTE = [&](int buf) {
    #pragma unroll
    for (int kk = 0; kk < 2; kk++) {
      short8 af[4], bfr[4];
      #pragma unroll
      for (int m = 0; m < 4; m++) af[m] = *(const short8*)&As[buf][(wm + m*16 + lr)*64 + kk*32 + lg*8];
      #pragma unroll
      for (int n = 0; n < 4; n++) bfr[n] = *(const short8*)&Bs[buf][(wn + n*16 + lr)*64 + kk*32 + lg*8];
      #pragma unroll
      for (int m = 0; m < 4; m++)
        #pragma unroll
        for (int n = 0; n < 4; n++)
          acc[m][n] = __builtin_amdgcn_mfma_f32_16x16x32_bf16(af[m], bfr[n], acc[m][n], 0, 0, 0);
    }
  };

  const int nt = K >> 6;                        // 16
  STAGE(0, 0);
  #pragma unroll 1
  for (int tt = 0; tt < nt - 1; ++tt) {
    int cur = tt & 1;
    STAGE(cur ^ 1, (tt + 1) * 64);              // prefetch next tile
    __builtin_amdgcn_sched_barrier(0);
    asm volatile("s_waitcnt vmcnt(8)" ::: "memory");   // cur's 8 loads done
    __builtin_amdgcn_s_barrier();
    __builtin_amdgcn_sched_barrier(0);
    COMPUTE(cur);
    __builtin_amdgcn_sched_barrier(0);
    __builtin_amdgcn_s_barrier();               // protect cur from next STAGE
  }
  asm volatile("s_waitcnt vmcnt(0)" ::: "memory");
  __builtin_amdgcn_s_barrier();
  __builtin_amdgcn_sched_barrier(0);
  COMPUTE((nt - 1) & 1);
  #undef STAGE

  #pragma unroll
  for (int m = 0; m < 4; m++)
    #pragma unroll
    for (int n = 0; n < 4; n++)
      #pragma unroll
      for (int r = 0; r < 4; r++) {
        int grow = bm*128 + wm + m*16 + lg*4 + r;
        int gcol = bn*128 + wn + n*16 + lr;
        size_t idx = (size_t)grow * N + gcol;
        if (BF_OUT) { Cb[idx] = f2bf(acc[m][n][r]); }
        else {
          float v = acc[m][n][r];
          if (RES) v += resid[idx];
          Cf[idx] = v;
        }
      }
}

// ---------------- post: q/k head-pair RMSNorm+RoPE  |  V transpose -----------
// blocks [0,10240): one wave = 2 heads of one row (packed short2 per lane).
// blocks [10240,10496): transpose V from qkv layout to Vt[b,kvh][d][pos].
__global__ __launch_bounds__(256)
void post2(const unsigned short* __restrict__ qkv,
           unsigned short* __restrict__ Qb, unsigned short* __restrict__ Kb,
           unsigned short* __restrict__ Vt){
  __shared__ short Vl[64 * 72];
  int blk = blockIdx.x;
  int t = threadIdx.x;
  if (blk < 10240) {
    int w = blk * 4 + (t >> 6);
    int lane = t & 63;
    int row = w / 10, hp = w % 10;               // hp<8: q pair, 8-9: k pair
    int b = row >> 11, pos = row & 2047;
    int ll = lane & 31, half = lane >> 5;
    unsigned int pk = *(const unsigned int*)(qkv + (size_t)row * 1536 + hp * 128 + 2 * lane);
    float v0 = bf2f((unsigned short)(pk & 0xFFFF));
    float v1 = bf2f((unsigned short)(pk >> 16));
    float ss = v0 * v0 + v1 * v1;
    #pragma unroll
    for (int m = 1; m < 32; m <<= 1) ss += __shfl_xor(ss, m);
    float sc = rsqrtf(ss * (1.f/64.f) + 1.1920929e-07f);
    v0 *= sc; v1 *= sc;
    float p0 = __shfl_xor(v0, 16);
    float p1 = __shfl_xor(v1, 16);
    int i0 = 2 * (ll & 15);
    const float cexp = -13.287712379549449f / 32.f;
    float f0 = (float)pos * exp2f((float)i0 * cexp);
    float f1 = (float)pos * exp2f((float)(i0 + 1) * cexp);
    float s0, c0, s1, c1;
    sincosf(f0, &s0, &c0);
    sincosf(f1, &s1, &c1);
    float o0, o1;
    if (ll < 16) { o0 = v0 * c0 - p0 * s0; o1 = v1 * c1 - p1 * s1; }
    else         { o0 = v0 * c0 + p0 * s0; o1 = v1 * c1 + p1 * s1; }
    unsigned int opk = (unsigned int)f2bf(o0) | ((unsigned int)f2bf(o1) << 16);
    if (hp < 8) {
      int head = 2 * hp + half;
      *(unsigned int*)(Qb + ((size_t)((b*16 + head) * 2048 + pos)) * 64 + 2 * ll) = opk;
    } else {
      int kvh = (hp - 8) * 2 + half;
      *(unsigned int*)(Kb + ((size_t)((b*4 + kvh) * 2048 + pos)) * 64 + 2 * ll) = opk;
    }
    return;
  }
  // ---- V transpose path ----
  int tb = blk - 10240;                          // [0,256)
  int b = tb >> 7, kvh = (tb >> 5) & 3, pblk = tb & 31;
  {
    int r = t >> 2, cs = (t & 3) * 16;
    int pos = pblk * 64 + r;
    const unsigned short* src = qkv + ((size_t)(b*2048 + pos)) * 1536 + 1280 + kvh * 64 + cs;
    short8 a0 = *(const short8*)(src);
    short8 a1 = *(const short8*)(src + 8);
    *(short8*)&Vl[r * 72 + cs]     = a0;
    *(short8*)&Vl[r * 72 + cs + 8] = a1;
  }
  __syncthreads();
  {
    int d = t >> 2, ps = (t & 3) * 16;
    short8 o0, o1;
    #pragma unroll
    for (int e = 0; e < 8; e++) o0[e] = Vl[(ps + e) * 72 + d];
    #pragma unroll
    for (int e = 0; e < 8; e++) o1[e] = Vl[(ps + 8 + e) * 72 + d];
    unsigned short* dst = Vt + ((size_t)((b*4 + kvh) * 64 + d)) * 2048 + pblk * 64 + ps;
    *(short8*)(dst)     = o0;
    *(short8*)(dst + 8) = o1;
  }
}

// ---------------- attention: one wave = 16 queries, contiguous key range ------
__global__ __launch_bounds__(256)
void attn(const unsigned short* __restrict__ Qb, const unsigned short* __restrict__ Kb,
          const unsigned short* __restrict__ Vt, const int* __restrict__ lo,
          unsigned short* __restrict__ Y){
  int blk = blockIdx.x;
  int qt = blk & 31, h = (blk >> 5) & 15, b = blk >> 9;
  int wv = threadIdx.x >> 6, lane = threadIdx.x & 63;
  int lr = lane & 15, lg = lane >> 4;
  int q0 = qt * 64 + wv * 16;
  const unsigned short* Qh = Qb + ((size_t)(b*16 + h)) * 2048 * 64;
  int kvh = h >> 2;
  const unsigned short* Kh = Kb + ((size_t)(b*4 + kvh)) * 2048 * 64;
  const unsigned short* Vh = Vt + ((size_t)(b*4 + kvh)) * 64 * 2048;
  short8 qa0 = *(const short8*)(Qh + (size_t)(q0 + lr) * 64 + lg * 8);
  short8 qa1 = *(const short8*)(Qh + (size_t)(q0 + lr) * 64 + 32 + lg * 8);
  const int* lop = lo + b * 2048 + q0;
  int4 mlv = *(const int4*)(lop + lg * 4);
  int mylo[4] = {mlv.x, mlv.y, mlv.z, mlv.w};
  int kc0 = lop[0] & ~31;
  int kend = q0 + 15;
  f32x4 oacc[4];
  #pragma unroll
  for (int n = 0; n < 4; n++) oacc[n] = (f32x4){0.f,0.f,0.f,0.f};
  float den[4] = {0.f,0.f,0.f,0.f};
  __shared__ __align__(16) short Pl[4][16 * 40];
  short* Pw = Pl[wv];
  for (int kc = kc0; kc <= kend; kc += 32) {
    f32x4 s[2];
    #pragma unroll
    for (int n = 0; n < 2; n++) {
      int kr = kc + n*16 + lr;
      int krl = min(kr, 2047);
      short8 k0 = *(const short8*)(Kh + (size_t)krl * 64 + lg * 8);
      short8 k1 = *(const short8*)(Kh + (size_t)krl * 64 + 32 + lg * 8);
      f32x4 z = (f32x4){0.f,0.f,0.f,0.f};
      z = __builtin_amdgcn_mfma_f32_16x16x32_bf16(qa0, k0, z, 0, 0, 0);
      z = __builtin_amdgcn_mfma_f32_16x16x32_bf16(qa1, k1, z, 0, 0, 0);
      s[n] = z;
    }
    #pragma unroll
    for (int n = 0; n < 2; n++)
      #pragma unroll
      for (int r = 0; r < 4; r++) {
        int krow = kc + n*16 + lr;
        int qrow = q0 + lg*4 + r;
        bool valid = (krow >= mylo[r]) && (krow <= qrow);
        float p = valid ? __expf(s[n][r] * 0.125f) : 0.f;
        den[r] += p;
        Pw[(lg*4 + r) * 40 + n*16 + lr] = (short)f2bf(p);
      }
    short8 pa = *(const short8*)&Pw[lr * 40 + lg * 8];
    int vc = min(kc + lg * 8, 2040);
    #pragma unroll
    for (int n = 0; n < 4; n++) {
      short8 vb = *(const short8*)(Vh + (size_t)(n*16 + lr) * 2048 + vc);
      oacc[n] = __builtin_amdgcn_mfma_f32_16x16x32_bf16(pa, vb, oacc[n], 0, 0, 0);
    }
  }
  #pragma unroll
  for (int r = 0; r < 4; r++)
    #pragma unroll
    for (int m = 1; m < 16; m <<= 1) den[r] += __shfl_xor(den[r], m);
  #pragma unroll
  for (int n = 0; n < 4; n++)
    #pragma unroll
    for (int r = 0; r < 4; r++) {
      int qrow = q0 + lg*4 + r;
      Y[((size_t)(b*2048 + qrow)) * 1024 + h*64 + n*16 + lr] = f2bf(oacc[n][r] / den[r]);
    }
}

extern "C" void kernel_launch(void* const* d_in, const int* in_sizes, int n_in,
                              void* d_out, int out_size, void* d_ws, size_t ws_size,
                              hipStream_t stream){
  const float* x    = (const float*)d_in[0];
  const float* wqkv = (const float*)d_in[1];
  const float* wout = (const float*)d_in[2];
  const unsigned char* mask = (const unsigned char*)d_in[3];
  float* out = (float*)d_out;
  char* ws = (char*)d_ws;
  size_t off = 0;
  auto alloc = [&](size_t bytes) -> void* {
    void* p = ws + off;
    off += (bytes + 255) & ~(size_t)255;
    return p;
  };
  unsigned short* wq_b  = (unsigned short*)alloc((size_t)1536*1024*2);
  unsigned short* wo_b  = (unsigned short*)alloc((size_t)1024*1024*2);
  unsigned short* h_b   = (unsigned short*)alloc((size_t)4096*1024*2);
  unsigned short* qkv_b = (unsigned short*)alloc((size_t)4096*1536*2);
  unsigned short* q_b   = (unsigned short*)alloc((size_t)4096*1024*2);
  unsigned short* k_b   = (unsigned short*)alloc((size_t)4096*256*2);
  unsigned short* vt_b  = (unsigned short*)alloc((size_t)4096*256*2);
  unsigned short* y_b   = (unsigned short*)alloc((size_t)4096*1024*2);
  int* lo               = (int*)alloc((size_t)4096*4);

  prep<<<2560 + 4096 + 2, 256, 0, stream>>>(wqkv, wout, wq_b, wo_b, x, h_b, mask, lo);
  gemm_nt<true,  false><<<384, 256, 0, stream>>>(h_b, wq_b, 4096, 1536, 1024, nullptr, qkv_b, nullptr);
  post2<<<10240 + 256, 256, 0, stream>>>(qkv_b, q_b, k_b, vt_b);
  attn<<<1024, 256, 0, stream>>>(q_b, k_b, vt_b, lo, y_b);
  gemm_nt<false, true><<<256, 256, 0, stream>>>(y_b, wo_b, 4096, 1024, 1024, out, nullptr, x);
}

// Round 5
// 145.653 us; speedup vs baseline: 1.1313x; 1.0754x over previous
//
#include <hip/hip_runtime.h>

typedef __attribute__((ext_vector_type(8))) short short8;
typedef __attribute__((ext_vector_type(4))) float f32x4;
typedef __attribute__((ext_vector_type(4))) unsigned short us4;

typedef unsigned int __attribute__((address_space(3))) lds_u32;
typedef const unsigned int __attribute__((address_space(1))) glb_u32;

__device__ __forceinline__ unsigned short f2bf(float f){
  unsigned int u = __float_as_uint(f);
  u = (u + 0x7FFFu + ((u >> 16) & 1u)) >> 16;
  return (unsigned short)u;
}
__device__ __forceinline__ float bf2f(unsigned short h){
  return __uint_as_float(((unsigned int)h) << 16);
}

// ---------------- fused prep: weight cast | rmsnorm(x) | lo-scan --------------
__global__ __launch_bounds__(256)
void prep(const float* __restrict__ wq, const float* __restrict__ wo,
          unsigned short* __restrict__ wqb, unsigned short* __restrict__ wob,
          const float* __restrict__ x, unsigned short* __restrict__ h,
          const unsigned char* __restrict__ mb, int* __restrict__ lo){
  int blk = blockIdx.x;
  int t = threadIdx.x;
  if (blk < 2560) {                                  // weight f32->bf16
    int i = blk * 256 + t;
    const int n1 = 1536 * 1024 / 4;
    float4 v = (i < n1) ? ((const float4*)wq)[i] : ((const float4*)wo)[i - n1];
    us4 o = { f2bf(v.x), f2bf(v.y), f2bf(v.z), f2bf(v.w) };
    if (i < n1) ((us4*)wqb)[i] = o;
    else        ((us4*)wob)[i - n1] = o;
    return;
  }
  if (blk < 2560 + 4096) {                           // rmsnorm over D=1024
    int row = blk - 2560;
    float4 v = ((const float4*)(x + (size_t)row * 1024))[t];
    float ss = v.x*v.x + v.y*v.y + v.z*v.z + v.w*v.w;
    #pragma unroll
    for (int m = 1; m < 64; m <<= 1) ss += __shfl_xor(ss, m);
    __shared__ float wsum[4];
    if ((t & 63) == 0) wsum[t >> 6] = ss;
    __syncthreads();
    float tot = wsum[0] + wsum[1] + wsum[2] + wsum[3];
    float sc = rsqrtf(tot * (1.f/1024.f) + 1.1920929e-07f);
    us4 o = { f2bf(v.x*sc), f2bf(v.y*sc), f2bf(v.z*sc), f2bf(v.w*sc) };
    *(us4*)(h + (size_t)row * 1024 + t * 4) = o;
    return;
  }
  // lo[q] = max(q-1023, last reset <= q); auto-detect mask dtype
  int b = blk - 2560 - 4096;
  __shared__ int flag_s;
  if (t == 0) flag_s = 0;
  __syncthreads();
  if (t < 64 && (t & 3) != 0 && mb[t] != 0) atomicOr(&flag_s, 1);
  __syncthreads();
  const bool isb = (flag_s != 0);
  const int* mi = (const int*)mb;
  int tmax = 0;
  int mvals[8];
  #pragma unroll
  for (int j = 0; j < 8; j++) {
    int p = t * 8 + j;
    int mv = isb ? (int)mb[b*2048 + p] : mi[b*2048 + p];
    mvals[j] = mv;
    if (mv) tmax = p;
  }
  __shared__ int sm[256];
  sm[t] = tmax;
  __syncthreads();
  for (int offd = 1; offd < 256; offd <<= 1) {
    int v = (t >= offd) ? sm[t - offd] : 0;
    __syncthreads();
    if (t >= offd) sm[t] = max(sm[t], v);
    __syncthreads();
  }
  int run = (t > 0) ? sm[t - 1] : 0;
  #pragma unroll
  for (int j = 0; j < 8; j++) {
    int p = t * 8 + j;
    if (mvals[j]) run = p;
    int l = run, wlo = p - 1023;
    if (wlo > l) l = wlo;
    if (l < 0) l = 0;
    lo[b*2048 + p] = l;
  }
}

// ---------------- NT GEMM 128x64 tile, 4 waves stacked, 2-phase dbuf ---------
// MODE 0: A=h, B=w_qkv; epilogue fuses per-head RMSNorm+RoPE, writes Qb/Kb/Vt.
// MODE 1: A=y,  B=w_out; epilogue adds residual, writes f32 out.
template<int MODE>
__global__ __launch_bounds__(256, 3)
void gemm64(const unsigned short* __restrict__ A, const unsigned short* __restrict__ Bw,
            unsigned short* __restrict__ Qb, unsigned short* __restrict__ Kb,
            unsigned short* __restrict__ Vt, float* __restrict__ Cf,
            const float* __restrict__ resid){
  constexpr int K = 1024;
  constexpr int NBN = (MODE == 0) ? 24 : 16;
  __shared__ __align__(16) short As[2][128 * 64];
  __shared__ __align__(16) short Bs[2][64 * 64];
  const int cpx = (NBN * 32) >> 3;
  const int swz = (blockIdx.x & 7) * cpx + (blockIdx.x >> 3);
  const int bm = swz / NBN, bn = swz % NBN;
  const int t = threadIdx.x, lane = t & 63, wv = t >> 6;
  const int lr = lane & 15, lg = lane >> 4;
  const int l8 = lane >> 3, c8 = (lane & 7) * 8;
  const int wr0 = wv * 32;

  f32x4 acc[2][4];
  #pragma unroll
  for (int m = 0; m < 2; m++)
    #pragma unroll
    for (int n = 0; n < 4; n++) acc[m][n] = (f32x4){0.f,0.f,0.f,0.f};

  const unsigned short* Ab = A + (size_t)(bm * 128) * K;
  const unsigned short* Bb = Bw + (size_t)(bn * 64) * K;

  // 24 chunks of 1KB: 16 for A (128x64), 8 for B (64x64); 6 per wave.
  #define STAGE(buf, kt) do { \
    _Pragma("unroll") \
    for (int i = 0; i < 6; i++) { \
      int c = wv * 6 + i; \
      if (c < 16) { \
        __builtin_amdgcn_global_load_lds((glb_u32*)(Ab + (size_t)(c*8 + l8) * K + (kt) + c8), \
                                         (lds_u32*)&As[buf][c * 512], 16, 0, 0); \
      } else { \
        __builtin_amdgcn_global_load_lds((glb_u32*)(Bb + (size_t)((c-16)*8 + l8) * K + (kt) + c8), \
                                         (lds_u32*)&Bs[buf][(c-16) * 512], 16, 0, 0); \
      } \
    } \
  } while (0)

  auto COMPUTE = [&](int buf) {
    #pragma unroll
    for (int kk = 0; kk < 2; kk++) {
      short8 af[2], bfr[4];
      #pragma unroll
      for (int m = 0; m < 2; m++) af[m] = *(const short8*)&As[buf][(wr0 + m*16 + lr)*64 + kk*32 + lg*8];
      #pragma unroll
      for (int n = 0; n < 4; n++) bfr[n] = *(const short8*)&Bs[buf][(n*16 + lr)*64 + kk*32 + lg*8];
      #pragma unroll
      for (int m = 0; m < 2; m++)
        #pragma unroll
        for (int n = 0; n < 4; n++)
          acc[m][n] = __builtin_amdgcn_mfma_f32_16x16x32_bf16(af[m], bfr[n], acc[m][n], 0, 0, 0);
    }
  };

  const int nt = K >> 6;                        // 16
  STAGE(0, 0);
  #pragma unroll 1
  for (int tt = 0; tt < nt - 1; ++tt) {
    int cur = tt & 1;
    STAGE(cur ^ 1, (tt + 1) * 64);              // prefetch next tile
    __builtin_amdgcn_sched_barrier(0);
    asm volatile("s_waitcnt vmcnt(6)" ::: "memory");   // cur's 6 loads done
    __builtin_amdgcn_s_barrier();
    __builtin_amdgcn_sched_barrier(0);
    COMPUTE(cur);
    __builtin_amdgcn_sched_barrier(0);
    __builtin_amdgcn_s_barrier();               // protect cur from next STAGE
  }
  asm volatile("s_waitcnt vmcnt(0)" ::: "memory");
  __builtin_amdgcn_s_barrier();
  __builtin_amdgcn_sched_barrier(0);
  COMPUTE((nt - 1) & 1);
  #undef STAGE

  if constexpr (MODE == 1) {
    #pragma unroll
    for (int m = 0; m < 2; m++)
      #pragma unroll
      for (int n = 0; n < 4; n++)
        #pragma unroll
        for (int r = 0; r < 4; r++) {
          int grow = bm*128 + wr0 + m*16 + lg*4 + r;
          int gcol = bn*64 + n*16 + lr;
          size_t idx = (size_t)grow * 1024 + gcol;
          Cf[idx] = acc[m][n][r] + resid[idx];
        }
  } else if (bn < 20) {
    // q/k heads: per-row RMSNorm (16-lane reduce) + lane-local RoPE
    const float cexp = -13.287712379549449f / 32.f;
    const float if0 = exp2f((float)lr * cexp);         // freq index lr   (n even)
    const float if1 = exp2f((float)(lr + 16) * cexp);  // freq index lr+16 (n odd)
    #pragma unroll
    for (int m = 0; m < 2; m++)
      #pragma unroll
      for (int r = 0; r < 4; r++) {
        float rs = acc[m][0][r]*acc[m][0][r] + acc[m][1][r]*acc[m][1][r]
                 + acc[m][2][r]*acc[m][2][r] + acc[m][3][r]*acc[m][3][r];
        #pragma unroll
        for (int msk = 1; msk < 16; msk <<= 1) rs += __shfl_xor(rs, msk);
        float sc = rsqrtf(rs * (1.f/64.f) + 1.1920929e-07f);
        int grow = bm*128 + wr0 + m*16 + lg*4 + r;
        int b = grow >> 11, pos = grow & 2047;
        float th0 = (float)pos * if0, th1 = (float)pos * if1;
        float s0, c0, s1, c1;
        sincosf(th0, &s0, &c0);
        sincosf(th1, &s1, &c1);
        float v0 = acc[m][0][r]*sc, v1 = acc[m][1][r]*sc;
        float v2 = acc[m][2][r]*sc, v3 = acc[m][3][r]*sc;
        float o0 = v0*c0 - v2*s0;       // col lr
        float o1 = v1*c1 - v3*s1;       // col 16+lr
        float o2 = v2*c0 + v0*s0;       // col 32+lr
        float o3 = v3*c1 + v1*s1;       // col 48+lr
        unsigned short* dst = (bn < 16)
          ? Qb + ((size_t)((b*16 + bn)      * 2048 + pos)) * 64
          : Kb + ((size_t)((b*4  + bn - 16) * 2048 + pos)) * 64;
        dst[lr]      = f2bf(o0);
        dst[16 + lr] = f2bf(o1);
        dst[32 + lr] = f2bf(o2);
        dst[48 + lr] = f2bf(o3);
      }
  } else {
    // v heads: transpose via swizzled LDS bounce, coalesced Vt stores
    short* Vl = &As[0][0];                       // 128 x 64 shorts
    #pragma unroll
    for (int m = 0; m < 2; m++)
      #pragma unroll
      for (int n = 0; n < 4; n++)
        #pragma unroll
        for (int r = 0; r < 4; r++) {
          int pl = wr0 + m*16 + lg*4 + r;        // pos within tile
          int d = n*16 + lr;
          Vl[pl * 64 + (d ^ ((pl & 7) << 3))] = (short)f2bf(acc[m][n][r]);
        }
    __syncthreads();
    int vh = bn - 20;
    int b = bm >> 4;
    int posg = (bm & 15) * 128;
    int pl = (t & 63) * 2, dbase = (t >> 6) * 16;
    #pragma unroll
    for (int dd = 0; dd < 16; dd++) {
      int d = dbase + dd;
      unsigned short w0 = (unsigned short)Vl[pl * 64 + (d ^ ((pl & 7) << 3))];
      unsigned short w1 = (unsigned short)Vl[(pl+1) * 64 + (d ^ (((pl+1) & 7) << 3))];
      unsigned int pk = (unsigned int)w0 | ((unsigned int)w1 << 16);
      *(unsigned int*)(Vt + ((size_t)((b*4 + vh)*64 + d)) * 2048 + posg + pl) = pk;
    }
  }
}

// ---------------- attention: one wave = 16 queries, contiguous key range ------
__global__ __launch_bounds__(256)
void attn(const unsigned short* __restrict__ Qb, const unsigned short* __restrict__ Kb,
          const unsigned short* __restrict__ Vt, const int* __restrict__ lo,
          unsigned short* __restrict__ Y){
  int blk = blockIdx.x;
  int qt = blk & 31, h = (blk >> 5) & 15, b = blk >> 9;
  int wv = threadIdx.x >> 6, lane = threadIdx.x & 63;
  int lr = lane & 15, lg = lane >> 4;
  int q0 = qt * 64 + wv * 16;
  const unsigned short* Qh = Qb + ((size_t)(b*16 + h)) * 2048 * 64;
  int kvh = h >> 2;
  const unsigned short* Kh = Kb + ((size_t)(b*4 + kvh)) * 2048 * 64;
  const unsigned short* Vh = Vt + ((size_t)(b*4 + kvh)) * 64 * 2048;
  short8 qa0 = *(const short8*)(Qh + (size_t)(q0 + lr) * 64 + lg * 8);
  short8 qa1 = *(const short8*)(Qh + (size_t)(q0 + lr) * 64 + 32 + lg * 8);
  const int* lop = lo + b * 2048 + q0;
  int4 mlv = *(const int4*)(lop + lg * 4);
  int mylo[4] = {mlv.x, mlv.y, mlv.z, mlv.w};
  int kc0 = lop[0] & ~31;
  int kend = q0 + 15;
  f32x4 oacc[4];
  #pragma unroll
  for (int n = 0; n < 4; n++) oacc[n] = (f32x4){0.f,0.f,0.f,0.f};
  float den[4] = {0.f,0.f,0.f,0.f};
  __shared__ __align__(16) short Pl[4][16 * 40];
  short* Pw = Pl[wv];
  for (int kc = kc0; kc <= kend; kc += 32) {
    f32x4 s[2];
    #pragma unroll
    for (int n = 0; n < 2; n++) {
      int kr = kc + n*16 + lr;
      int krl = min(kr, 2047);
      short8 k0 = *(const short8*)(Kh + (size_t)krl * 64 + lg * 8);
      short8 k1 = *(const short8*)(Kh + (size_t)krl * 64 + 32 + lg * 8);
      f32x4 z = (f32x4){0.f,0.f,0.f,0.f};
      z = __builtin_amdgcn_mfma_f32_16x16x32_bf16(qa0, k0, z, 0, 0, 0);
      z = __builtin_amdgcn_mfma_f32_16x16x32_bf16(qa1, k1, z, 0, 0, 0);
      s[n] = z;
    }
    #pragma unroll
    for (int n = 0; n < 2; n++)
      #pragma unroll
      for (int r = 0; r < 4; r++) {
        int krow = kc + n*16 + lr;
        int qrow = q0 + lg*4 + r;
        bool valid = (krow >= mylo[r]) && (krow <= qrow);
        float p = valid ? __expf(s[n][r] * 0.125f) : 0.f;
        den[r] += p;
        Pw[(lg*4 + r) * 40 + n*16 + lr] = (short)f2bf(p);
      }
    short8 pa = *(const short8*)&Pw[lr * 40 + lg * 8];
    int vc = min(kc + lg * 8, 2040);
    #pragma unroll
    for (int n = 0; n < 4; n++) {
      short8 vb = *(const short8*)(Vh + (size_t)(n*16 + lr) * 2048 + vc);
      oacc[n] = __builtin_amdgcn_mfma_f32_16x16x32_bf16(pa, vb, oacc[n], 0, 0, 0);
    }
  }
  #pragma unroll
  for (int r = 0; r < 4; r++)
    #pragma unroll
    for (int m = 1; m < 16; m <<= 1) den[r] += __shfl_xor(den[r], m);
  #pragma unroll
  for (int n = 0; n < 4; n++)
    #pragma unroll
    for (int r = 0; r < 4; r++) {
      int qrow = q0 + lg*4 + r;
      Y[((size_t)(b*2048 + qrow)) * 1024 + h*64 + n*16 + lr] = f2bf(oacc[n][r] / den[r]);
    }
}

extern "C" void kernel_launch(void* const* d_in, const int* in_sizes, int n_in,
                              void* d_out, int out_size, void* d_ws, size_t ws_size,
                              hipStream_t stream){
  const float* x    = (const float*)d_in[0];
  const float* wqkv = (const float*)d_in[1];
  const float* wout = (const float*)d_in[2];
  const unsigned char* mask = (const unsigned char*)d_in[3];
  float* out = (float*)d_out;
  char* ws = (char*)d_ws;
  size_t off = 0;
  auto alloc = [&](size_t bytes) -> void* {
    void* p = ws + off;
    off += (bytes + 255) & ~(size_t)255;
    return p;
  };
  unsigned short* wq_b  = (unsigned short*)alloc((size_t)1536*1024*2);
  unsigned short* wo_b  = (unsigned short*)alloc((size_t)1024*1024*2);
  unsigned short* h_b   = (unsigned short*)alloc((size_t)4096*1024*2);
  unsigned short* q_b   = (unsigned short*)alloc((size_t)4096*1024*2);
  unsigned short* k_b   = (unsigned short*)alloc((size_t)4096*256*2);
  unsigned short* vt_b  = (unsigned short*)alloc((size_t)4096*256*2);
  unsigned short* y_b   = (unsigned short*)alloc((size_t)4096*1024*2);
  int* lo               = (int*)alloc((size_t)4096*4);

  prep<<<2560 + 4096 + 2, 256, 0, stream>>>(wqkv, wout, wq_b, wo_b, x, h_b, mask, lo);
  gemm64<0><<<768, 256, 0, stream>>>(h_b, wq_b, q_b, k_b, vt_b, nullptr, nullptr);
  attn<<<1024, 256, 0, stream>>>(q_b, k_b, vt_b, lo, y_b);
  gemm64<1><<<512, 256, 0, stream>>>(y_b, wo_b, nullptr, nullptr, nullptr, out, x);
}